// Round 10
// baseline (307.797 us; speedup 1.0000x reference)
//
#include <hip/hip_runtime.h>

#define NEGV -10000.0f
constexpr int K  = 128;   // states
constexpr int T  = 512;   // timesteps
constexpr int CH = 8;     // h-prefetch chunk (timesteps)

typedef float f32x2 __attribute__((ext_vector_type(2)));
typedef float f32x4 __attribute__((ext_vector_type(4)));

// s_barrier WITHOUT the compiler's vmcnt(0) drain.
__device__ __forceinline__ void bar_lgkm() {
  asm volatile("s_waitcnt lgkmcnt(0)\n\ts_barrier" ::: "memory");
}
__device__ __forceinline__ void wait_vm0() {
  asm volatile("s_waitcnt vmcnt(0)" ::: "memory");
}
// async global -> LDS, 16B/lane; LDS dest = wave-uniform base + lane*16
__device__ __forceinline__ void dma16(const float* g, float* l) {
  __builtin_amdgcn_global_load_lds(
      (const __attribute__((address_space(1))) void*)g,
      (__attribute__((address_space(3))) void*)l, 16, 0, 0);
}
template <int CTRL>
__device__ __forceinline__ float dpp_add(float x) {
  int o = __builtin_amdgcn_update_dpp(0, __float_as_int(x), CTRL, 0xF, 0xF, true);
  return x + __int_as_float(o);
}
// sum across the 16 lanes of a k-group row: 4 DPP butterfly steps
__device__ __forceinline__ float sum16(float x) {
  x = dpp_add<0xB1>(x);    // + lane^1 (quad_perm [1,0,3,2])
  x = dpp_add<0x4E>(x);    // + lane^2 (quad_perm [2,3,0,1])
  x = dpp_add<0x141>(x);   // + lane^4 (row_half_mirror)
  x = dpp_add<0x140>(x);   // + other 8-half (row_mirror)
  return x;
}

#if __has_builtin(__builtin_elementwise_fma)
#define VFMA(a, b, c) __builtin_elementwise_fma((a), (b), (c))
#else
__device__ __forceinline__ f32x2 VFMA(f32x2 a, f32x2 b, f32x2 c) {
  f32x2 r; r.x = fmaf(a.x, b.x, c.x); r.y = fmaf(a.y, b.y, c.y); return r;
}
#endif

// S=8 re-tiling of the R9 skeleton. R9 post-mortem: E-resident, conflicts 0,
// VALUBusy 22% -> the 940-cyc/step chain is dominated by the post-barrier
// LDS burst (24 DS instr/CU/step into one pipe) + serial turnaround; DS
// instr count is the term that has empirically moved lambda (R4->R9:
// 36->24 instrs, -320 cyc). Thread = (state-group of 8 = 32*wid+8*sgl,
// k-group of 8 floats): E still 64 floats/thread (RA-proven budget), DS
// drops to ~17/CU/step: p 2 b128/thread (8/CU), hv 1/wave via kg-parity
// split, write 1 masked b128/wave. Half-line swap s=(kg>>2)&1 on BOTH the
// E-load and p-read makes each read instr exactly 2-way/bank (free, m136).
// Combine over 16 lanes = 4-step DPP butterfly. Writers = kg<2 lanes;
// fs = log(pw) + S_chunk (algebraically identical, ~1e-6 ulp change).
// Chunk-stale rescale + dma16 staging + barrier cadence carried from R9.
__global__ __attribute__((amdgpu_flat_work_group_size(256, 256),
                          amdgpu_waves_per_eu(1, 1)))
void crf_fwd(const float* __restrict__ h, const float* __restrict__ trans,
             const float* __restrict__ mask, float* __restrict__ out) {
  const int tid  = threadIdx.x;     // 0..255
  const int b    = blockIdx.x;
  const int wid  = tid >> 6;        // wave 0..3
  const int lane = tid & 63;
  const int sgl  = lane >> 4;       // state-group-in-wave 0..3
  const int kg   = lane & 15;       // k-group 0..15 (8 floats each)
  const int sb   = 32 * wid + 8 * sgl;  // states sb..sb+7
  const int s    = (kg >> 2) & 1;   // half-line swap (bank spread)
  const int kA   = 8 * kg + 4 * s;        // first 16B chunk (floats)
  const int kB   = 8 * kg + 4 * (1 - s);  // second 16B chunk

  __shared__ __align__(16) float p_lds[2][K];          // double-buffered p
  __shared__ __align__(16) float hbuf[2][4][CH][32];   // [buf][wave][row][col]
  __shared__ float Mslot[2];                           // tracker, per-chunk parity
  __shared__ float red[8];

  // ---- len = sum(mask[b,:]) (contiguous prefix of 1s) ----
  float msum = mask[b * T + tid] + mask[b * T + 256 + tid];
  #pragma unroll
  for (int off = 32; off > 0; off >>= 1) msum += __shfl_xor(msum, off);
  if (lane == 0) red[wid] = msum;

  // ---- async prefetch of h chunk 0; wave w loads its own 32-col slice ----
  const float* hb = h + (size_t)b * T * K;
  dma16(hb + (size_t)(lane >> 3) * K + 32 * wid + 4 * (lane & 7),
        &hbuf[0][wid][0][0]);

  // ---- E: 8 states x two swapped 4-float k-chunks, exp'd, f32x2-split ----
#define EXP4(v) v.x = __expf(v.x); v.y = __expf(v.y); \
                v.z = __expf(v.z); v.w = __expf(v.w);
#define LDE(si) \
  const float* rp##si = trans + (size_t)(sb + si) * K; \
  f32x4 wA##si = *reinterpret_cast<const f32x4*>(rp##si + kA); \
  f32x4 wB##si = *reinterpret_cast<const f32x4*>(rp##si + kB); \
  EXP4(wA##si) EXP4(wB##si) \
  f32x2 EA##si##l = __builtin_shufflevector(wA##si, wA##si, 0, 1); \
  f32x2 EA##si##h = __builtin_shufflevector(wA##si, wA##si, 2, 3); \
  f32x2 EB##si##l = __builtin_shufflevector(wB##si, wB##si, 0, 1); \
  f32x2 EB##si##h = __builtin_shufflevector(wB##si, wB##si, 2, 3);
  LDE(0) LDE(1) LDE(2) LDE(3) LDE(4) LDE(5) LDE(6) LDE(7)
#undef LDE
#undef EXP4
#define PIN(si) asm volatile("" : "+v"(EA##si##l), "+v"(EA##si##h), \
    "+v"(EB##si##l), "+v"(EB##si##h));
  PIN(0) PIN(1) PIN(2) PIN(3) PIN(4) PIN(5) PIN(6) PIN(7)
#undef PIN
  // trans[EOS=1, my 4 fs states] (writers: kg 0 -> sb..sb+3, kg 1 -> sb+4..7)
  const f32x4 trE = *reinterpret_cast<const f32x4*>(trans + K + sb + 4 * (kg & 1));

  // ---- init: p(0) one-hot at SOS; tracker = 0 ----
  if (tid < K) p_lds[0][tid] = (tid == 0) ? 1.0f : 0.0f;
  if (tid < 2) Mslot[tid] = 0.0f;
  bar_lgkm();

  const int len = (int)(red[0] + red[1] + red[2] + red[3] + 0.5f);
  const int nch = (len + CH - 1) >> 3;

  float Scur = 0.0f;                          // shift of the p about to be read
  f32x4 fs4 = {NEGV, NEGV, NEGV, NEGV};       // writers' 4 true scores

  for (int mc = 0; mc < nch; ++mc) {
    const int base = mc << 3;
    const int cur  = mc & 1;
    #pragma unroll
    for (int c = 0; c < CH; ++c) {
      const int t = base + c;
      if (t >= len) break;               // uniform per block
      bar_lgkm();                        // p(t), Mslot writes now visible

      float Snext = Scur;
      if (c == 0) {                      // chunk boundary
        wait_vm0();
        const int tn = t + CH;
        if (tn < len) {
          dma16(hb + (size_t)(tn + (lane >> 3)) * K + 32 * wid + 4 * (lane & 7),
                &hbuf[cur ^ 1][wid][0][0]);
        }
        if (mc) Snext = Mslot[mc & 1];   // fresh tracker (written at cpos 7)
      }

      // hv: kg-parity split -- kg even reads states sb..sb+3, odd sb+4..7
      const f32x4 hv4 = *reinterpret_cast<const f32x4*>(
          &hbuf[cur][wid][c][8 * sgl + 4 * (kg & 1)]);

      // 8-wide k-slice dots for 8 states; swapped 2x b128 reads (2-way free)
      const float* pb = p_lds[c & 1];
      const f32x4 qA = *reinterpret_cast<const f32x4*>(pb + kA);
      const f32x4 qB = *reinterpret_cast<const f32x4*>(pb + kB);
      const f32x2 qAl = __builtin_shufflevector(qA, qA, 0, 1);
      const f32x2 qAh = __builtin_shufflevector(qA, qA, 2, 3);
      const f32x2 qBl = __builtin_shufflevector(qB, qB, 0, 1);
      const f32x2 qBh = __builtin_shufflevector(qB, qB, 2, 3);
#define DOTSI(si) \
      f32x2 u##si = {0.f, 0.f}, v##si = {0.f, 0.f}; \
      u##si = VFMA(EA##si##l, qAl, u##si); v##si = VFMA(EA##si##h, qAh, v##si); \
      u##si = VFMA(EB##si##l, qBl, u##si); v##si = VFMA(EB##si##h, qBh, v##si); \
      const float tot##si = sum16((u##si.x + u##si.y) + (v##si.x + v##si.y));
      DOTSI(0) DOTSI(1) DOTSI(2) DOTSI(3)
      DOTSI(4) DOTSI(5) DOTSI(6) DOTSI(7)
#undef DOTSI

      // writers (kg<2): pw for 4 states, masked exp/mul/write
      const float dshift = Scur - Snext;   // nonzero only at chunk head
      if (kg < 2) {
        f32x4 eh;
        eh.x = __expf(hv4.x + dshift); eh.y = __expf(hv4.y + dshift);
        eh.z = __expf(hv4.z + dshift); eh.w = __expf(hv4.w + dshift);
        f32x4 pw;
        pw.x = (kg == 0 ? tot0 : tot4) * eh.x;
        pw.y = (kg == 0 ? tot1 : tot5) * eh.y;
        pw.z = (kg == 0 ? tot2 : tot6) * eh.z;
        pw.w = (kg == 0 ? tot3 : tot7) * eh.w;
        *reinterpret_cast<f32x4*>(&p_lds[(c & 1) ^ 1][sb + 4 * kg]) = pw;

        if (c == CH - 1 || t == len - 1) {   // logs off the per-step path
          fs4.x = __logf(pw.x) + Snext;      // fs = log(pw) + S_chunk
          fs4.y = __logf(pw.y) + Snext;
          fs4.z = __logf(pw.z) + Snext;
          fs4.w = __logf(pw.w) + Snext;
          if (tid == 0) Mslot[(mc + 1) & 1] = fs4.z;   // tracker = state j=2
        }
      }
      Scur = Snext;
    }
  }

  // ---- epilogue: out[b] = logsumexp_j(fs_j + trans[EOS, j]) ----
  // Each of the 128 states appears exactly once across the kg<2 lanes.
  f32x4 ff;
  if (kg < 2) {
    ff.x = fs4.x + trE.x; ff.y = fs4.y + trE.y;
    ff.z = fs4.z + trE.z; ff.w = fs4.w + trE.w;
  } else {
    ff.x = NEGV; ff.y = NEGV; ff.z = NEGV; ff.w = NEGV;
  }
  float mx = fmaxf(fmaxf(ff.x, ff.y), fmaxf(ff.z, ff.w));
  #pragma unroll
  for (int off = 32; off > 0; off >>= 1) mx = fmaxf(mx, __shfl_xor(mx, off));
  if (lane == 0) red[wid] = mx;
  bar_lgkm();
  const float fm = fmaxf(fmaxf(red[0], red[1]), fmaxf(red[2], red[3]));
  float e = (__expf(ff.x - fm) + __expf(ff.y - fm)) +
            (__expf(ff.z - fm) + __expf(ff.w - fm));   // kg>=2 -> exp(-1e4)=0
  #pragma unroll
  for (int off = 32; off > 0; off >>= 1) e += __shfl_xor(e, off);
  if (lane == 0) red[4 + wid] = e;
  bar_lgkm();
  if (tid == 0) out[b] = fm + __logf((red[4] + red[5]) + (red[6] + red[7]));
}

extern "C" void kernel_launch(void* const* d_in, const int* in_sizes, int n_in,
                              void* d_out, int out_size, void* d_ws, size_t ws_size,
                              hipStream_t stream) {
  const float* h     = (const float*)d_in[0];  // (B,T,K) fp32
  const float* trans = (const float*)d_in[1];  // (K,K)   fp32
  const float* mask  = (const float*)d_in[2];  // (B,T)   fp32
  float* out = (float*)d_out;                  // (B,)    fp32
  const int B = in_sizes[0] / (T * K);         // 256
  crf_fwd<<<B, 256, 0, stream>>>(h, trans, mask, out);
}

// Round 11
// 273.885 us; speedup vs baseline: 1.1238x; 1.1238x over previous
//
#include <hip/hip_runtime.h>

#define NEGV -10000.0f
constexpr int K  = 128;   // states
constexpr int T  = 512;   // timesteps
constexpr int CH = 8;     // h chunk (timesteps) held in registers

typedef float f32x2 __attribute__((ext_vector_type(2)));
typedef float f32x4 __attribute__((ext_vector_type(4)));

// s_barrier WITHOUT the compiler's vmcnt(0) drain.
__device__ __forceinline__ void bar_lgkm() {
  asm volatile("s_waitcnt lgkmcnt(0)\n\ts_barrier" ::: "memory");
}
template <int CTRL>
__device__ __forceinline__ float dpp_add(float x) {
  int o = __builtin_amdgcn_update_dpp(0, __float_as_int(x), CTRL, 0xF, 0xF, true);
  return x + __int_as_float(o);
}
// sum across the 8 lanes of an oct-group: 3 DPP butterfly steps
__device__ __forceinline__ float sum8(float x) {
  x = dpp_add<0xB1>(x);    // + lane^1 (quad_perm [1,0,3,2])
  x = dpp_add<0x4E>(x);    // + lane^2 (quad_perm [2,3,0,1])
  x = dpp_add<0x141>(x);   // + other quad (row_half_mirror)
  return x;
}

#if __has_builtin(__builtin_elementwise_fma)
#define VFMA(a, b, c) __builtin_elementwise_fma((a), (b), (c))
#else
__device__ __forceinline__ f32x2 VFMA(f32x2 a, f32x2 b, f32x2 c) {
  f32x2 r; r.x = fmaf(a.x, b.x, c.x); r.y = fmaf(a.y, b.y, c.y); return r;
}
#endif

// R9 skeleton (S=4/G=16, the measured optimum of the tiling family: R10's
// S=8 deepened the DPP tree and LOST 210 cyc/step) with ONE change: h moved
// from LDS staging (dma16+hbuf+4 ds_read/step) to a register double-buffer.
// Thread = (gl 0..7 -> states sb..sb+3, oct 0..7 -> rotated 16-float
// k-slice). E = 64 floats/thread in named pinned registers (RA-proven).
// h[t, sb..sb+3] is thread-private -> 2x8 named f32x4 (64 VGPR), chunk
// mc+1 prefetched at the head of chunk mc, landing under ~7000 cyc of
// compute. Deletes per step: 4 hv ds_reads + dma16 LDS writes + the
// chunk-head wait_vm0. Chunk body is an explicit 8-step macro so every
// h-register index is compile-time (no scratch). Chunk-stale rescale,
// rotation, sum8, writer masking, epilogue: byte-identical to R9.
__global__ __attribute__((amdgpu_flat_work_group_size(256, 256),
                          amdgpu_waves_per_eu(1, 1)))
void crf_fwd(const float* __restrict__ h, const float* __restrict__ trans,
             const float* __restrict__ mask, float* __restrict__ out) {
  const int tid  = threadIdx.x;     // 0..255
  const int b    = blockIdx.x;
  const int wid  = tid >> 6;        // wave 0..3
  const int lane = tid & 63;
  const int gl   = lane >> 3;       // group-in-wave 0..7
  const int oct  = lane & 7;        // k-slice 0..7
  const int sb   = 4 * (8 * wid + gl);  // states sb..sb+3
  const int rot  = oct >> 1;
  const int k0   = 16 * oct + 4 * ((0 + rot) & 3);
  const int k1   = 16 * oct + 4 * ((1 + rot) & 3);
  const int k2   = 16 * oct + 4 * ((2 + rot) & 3);
  const int k3   = 16 * oct + 4 * ((3 + rot) & 3);

  __shared__ __align__(16) float p_lds[2][K];          // double-buffered p
  __shared__ float Mslot[2];                           // tracker, per-chunk parity
  __shared__ float red[8];

  // ---- len = sum(mask[b,:]) (contiguous prefix of 1s) ----
  float msum = mask[b * T + tid] + mask[b * T + 256 + tid];
  #pragma unroll
  for (int off = 32; off > 0; off >>= 1) msum += __shfl_xor(msum, off);
  if (lane == 0) red[wid] = msum;

  // ---- E: 4 states x 16 k-floats in NAMED registers, exp'd, f32x2-split ----
#define EXP4(v) v.x = __expf(v.x); v.y = __expf(v.y); \
                v.z = __expf(v.z); v.w = __expf(v.w);
#define LDE(si) \
  const float* rp##si = trans + (size_t)(sb + si) * K; \
  f32x4 w##si##0 = *reinterpret_cast<const f32x4*>(rp##si + k0); \
  f32x4 w##si##1 = *reinterpret_cast<const f32x4*>(rp##si + k1); \
  f32x4 w##si##2 = *reinterpret_cast<const f32x4*>(rp##si + k2); \
  f32x4 w##si##3 = *reinterpret_cast<const f32x4*>(rp##si + k3); \
  EXP4(w##si##0) EXP4(w##si##1) EXP4(w##si##2) EXP4(w##si##3) \
  f32x2 E##si##0l = __builtin_shufflevector(w##si##0, w##si##0, 0, 1); \
  f32x2 E##si##0h = __builtin_shufflevector(w##si##0, w##si##0, 2, 3); \
  f32x2 E##si##1l = __builtin_shufflevector(w##si##1, w##si##1, 0, 1); \
  f32x2 E##si##1h = __builtin_shufflevector(w##si##1, w##si##1, 2, 3); \
  f32x2 E##si##2l = __builtin_shufflevector(w##si##2, w##si##2, 0, 1); \
  f32x2 E##si##2h = __builtin_shufflevector(w##si##2, w##si##2, 2, 3); \
  f32x2 E##si##3l = __builtin_shufflevector(w##si##3, w##si##3, 0, 1); \
  f32x2 E##si##3h = __builtin_shufflevector(w##si##3, w##si##3, 2, 3);
  LDE(0) LDE(1) LDE(2) LDE(3)
#undef LDE
#undef EXP4
#define PIN(si) asm volatile("" : "+v"(E##si##0l), "+v"(E##si##0h), \
    "+v"(E##si##1l), "+v"(E##si##1h), "+v"(E##si##2l), "+v"(E##si##2h), \
    "+v"(E##si##3l), "+v"(E##si##3h));
  PIN(0) PIN(1) PIN(2) PIN(3)
#undef PIN
  const f32x4 trE = *reinterpret_cast<const f32x4*>(trans + K + sb); // trans[EOS=1, sb..sb+3]

  // ---- h register double-buffer; thread reads h[b, t, sb..sb+3] ----
  const float* hT = h + (size_t)b * T * K + sb;
  f32x4 hA0, hA1, hA2, hA3, hA4, hA5, hA6, hA7;     // chunk buffer A
  f32x4 hB0 = {0,0,0,0}, hB1 = {0,0,0,0}, hB2 = {0,0,0,0}, hB3 = {0,0,0,0},
        hB4 = {0,0,0,0}, hB5 = {0,0,0,0}, hB6 = {0,0,0,0}, hB7 = {0,0,0,0};
#define LDH(BUF, t0) \
  BUF##0 = *reinterpret_cast<const f32x4*>(hT + (size_t)((t0) + 0) * K); \
  BUF##1 = *reinterpret_cast<const f32x4*>(hT + (size_t)((t0) + 1) * K); \
  BUF##2 = *reinterpret_cast<const f32x4*>(hT + (size_t)((t0) + 2) * K); \
  BUF##3 = *reinterpret_cast<const f32x4*>(hT + (size_t)((t0) + 3) * K); \
  BUF##4 = *reinterpret_cast<const f32x4*>(hT + (size_t)((t0) + 4) * K); \
  BUF##5 = *reinterpret_cast<const f32x4*>(hT + (size_t)((t0) + 5) * K); \
  BUF##6 = *reinterpret_cast<const f32x4*>(hT + (size_t)((t0) + 6) * K); \
  BUF##7 = *reinterpret_cast<const f32x4*>(hT + (size_t)((t0) + 7) * K); \
  asm volatile("" : "+v"(BUF##0), "+v"(BUF##1), "+v"(BUF##2), "+v"(BUF##3), \
                    "+v"(BUF##4), "+v"(BUF##5), "+v"(BUF##6), "+v"(BUF##7));
  LDH(hA, 0)                                        // prologue: chunk 0

  // ---- init: p(0) one-hot at SOS; tracker = 0 ----
  if (tid < K) p_lds[0][tid] = (tid == 0) ? 1.0f : 0.0f;
  if (tid < 2) Mslot[tid] = 0.0f;
  bar_lgkm();

  const int len = (int)(red[0] + red[1] + red[2] + red[3] + 0.5f);
  const int nch = (len + CH - 1) >> 3;

  float Scur = 0.0f;            // shift of the p about to be read
  float fsA = NEGV, fsB = NEGV, fsC = NEGV, fsD = NEGV;

  // ---- one timestep; cc is a literal 0..7, CUR##cc a named register ----
#define STEP(cc, CUR, NXT, MC, BASE)                                         \
  if ((BASE) + (cc) < len) {                                                 \
    bar_lgkm();                       /* p(t), Mslot writes now visible */   \
    float Snext = Scur;                                                      \
    if ((cc) == 0) {                  /* chunk head */                       \
      if (MC) Snext = Mslot[(MC) & 1];                                       \
      if ((BASE) + CH < len) { LDH(NXT, (BASE) + CH) }  /* prefetch */       \
    }                                                                        \
    const f32x4 hv4 = CUR##cc;                                               \
    const float* pb = p_lds[(cc) & 1];                                       \
    const f32x4 qq0 = *reinterpret_cast<const f32x4*>(pb + k0);              \
    const f32x4 qq1 = *reinterpret_cast<const f32x4*>(pb + k1);              \
    const f32x4 qq2 = *reinterpret_cast<const f32x4*>(pb + k2);              \
    const f32x4 qq3 = *reinterpret_cast<const f32x4*>(pb + k3);              \
    const f32x2 q0l = __builtin_shufflevector(qq0, qq0, 0, 1);               \
    const f32x2 q0h = __builtin_shufflevector(qq0, qq0, 2, 3);               \
    const f32x2 q1l = __builtin_shufflevector(qq1, qq1, 0, 1);               \
    const f32x2 q1h = __builtin_shufflevector(qq1, qq1, 2, 3);               \
    const f32x2 q2l = __builtin_shufflevector(qq2, qq2, 0, 1);               \
    const f32x2 q2h = __builtin_shufflevector(qq2, qq2, 2, 3);               \
    const f32x2 q3l = __builtin_shufflevector(qq3, qq3, 0, 1);               \
    const f32x2 q3h = __builtin_shufflevector(qq3, qq3, 2, 3);               \
    DOTSI(0) DOTSI(1) DOTSI(2) DOTSI(3)                                      \
    const float dsh = Scur - Snext;   /* nonzero only at chunk head */       \
    if (oct == 0) {                                                          \
      f32x4 pw;                                                              \
      pw.x = tot0 * __expf(hv4.x + dsh);                                     \
      pw.y = tot1 * __expf(hv4.y + dsh);                                     \
      pw.z = tot2 * __expf(hv4.z + dsh);                                     \
      pw.w = tot3 * __expf(hv4.w + dsh);                                     \
      *reinterpret_cast<f32x4*>(&p_lds[((cc) & 1) ^ 1][sb]) = pw;            \
    }                                                                        \
    if ((cc) == CH - 1 || (BASE) + (cc) == len - 1) {                        \
      fsA = hv4.x + Scur + __logf(tot0);                                     \
      fsB = hv4.y + Scur + __logf(tot1);                                     \
      fsC = hv4.z + Scur + __logf(tot2);                                     \
      fsD = hv4.w + Scur + __logf(tot3);                                     \
      if (tid == 0) Mslot[((MC) + 1) & 1] = fsC;   /* tracker = state 2 */   \
    }                                                                        \
    Scur = Snext;                                                            \
  }

#define DOTSI(si) \
      f32x2 u##si = {0.f, 0.f}, v##si = {0.f, 0.f}; \
      u##si = VFMA(E##si##0l, q0l, u##si); v##si = VFMA(E##si##0h, q0h, v##si); \
      u##si = VFMA(E##si##1l, q1l, u##si); v##si = VFMA(E##si##1h, q1h, v##si); \
      u##si = VFMA(E##si##2l, q2l, u##si); v##si = VFMA(E##si##2h, q2h, v##si); \
      u##si = VFMA(E##si##3l, q3l, u##si); v##si = VFMA(E##si##3h, q3h, v##si); \
      const float tot##si = sum8((u##si.x + u##si.y) + (v##si.x + v##si.y));

#define CHUNK(CUR, NXT, MC, BASE)                                            \
  { STEP(0, CUR, NXT, MC, BASE) STEP(1, CUR, NXT, MC, BASE)                  \
    STEP(2, CUR, NXT, MC, BASE) STEP(3, CUR, NXT, MC, BASE)                  \
    STEP(4, CUR, NXT, MC, BASE) STEP(5, CUR, NXT, MC, BASE)                  \
    STEP(6, CUR, NXT, MC, BASE) STEP(7, CUR, NXT, MC, BASE) }

  for (int mc = 0; mc < nch; mc += 2) {
    CHUNK(hA, hB, mc, mc << 3)
    if (mc + 1 < nch) { CHUNK(hB, hA, mc + 1, (mc + 1) << 3) }
  }
#undef CHUNK
#undef DOTSI
#undef STEP
#undef LDH

  // ---- epilogue: out[b] = logsumexp_j(fs_j + trans[EOS, j]) ----
  f32x4 ff;
  ff.x = fsA + trE.x; ff.y = fsB + trE.y;
  ff.z = fsC + trE.z; ff.w = fsD + trE.w;
  float mx = fmaxf(fmaxf(ff.x, ff.y), fmaxf(ff.z, ff.w));
  #pragma unroll
  for (int off = 32; off > 0; off >>= 1) mx = fmaxf(mx, __shfl_xor(mx, off));
  if (lane == 0) red[wid] = mx;
  bar_lgkm();
  const float fm = fmaxf(fmaxf(red[0], red[1]), fmaxf(red[2], red[3]));
  float e = 0.0f;
  if (oct == 0)                         // de-dup the 8 slice copies
    e = (__expf(ff.x - fm) + __expf(ff.y - fm)) +
        (__expf(ff.z - fm) + __expf(ff.w - fm));
  #pragma unroll
  for (int off = 32; off > 0; off >>= 1) e += __shfl_xor(e, off);
  if (lane == 0) red[4 + wid] = e;
  bar_lgkm();
  if (tid == 0) out[b] = fm + __logf((red[4] + red[5]) + (red[6] + red[7]));
}

extern "C" void kernel_launch(void* const* d_in, const int* in_sizes, int n_in,
                              void* d_out, int out_size, void* d_ws, size_t ws_size,
                              hipStream_t stream) {
  const float* h     = (const float*)d_in[0];  // (B,T,K) fp32
  const float* trans = (const float*)d_in[1];  // (K,K)   fp32
  const float* mask  = (const float*)d_in[2];  // (B,T)   fp32
  float* out = (float*)d_out;                  // (B,)    fp32
  const int B = in_sizes[0] / (T * K);         // 256
  crf_fwd<<<B, 256, 0, stream>>>(h, trans, mask, out);
}

// Round 12
// 256.092 us; speedup vs baseline: 1.2019x; 1.0695x over previous
//
#include <hip/hip_runtime.h>

#define NEGV -10000.0f
constexpr int K  = 128;   // states
constexpr int T  = 512;   // timesteps
constexpr int CH = 8;     // h chunk (timesteps) held in registers

typedef float f32x2 __attribute__((ext_vector_type(2)));
typedef float f32x4 __attribute__((ext_vector_type(4)));

// s_barrier WITHOUT the compiler's vmcnt(0) drain.
__device__ __forceinline__ void bar_lgkm() {
  asm volatile("s_waitcnt lgkmcnt(0)\n\ts_barrier" ::: "memory");
}
template <int CTRL>
__device__ __forceinline__ float dpp_add(float x) {
  int o = __builtin_amdgcn_update_dpp(0, __float_as_int(x), CTRL, 0xF, 0xF, true);
  return x + __int_as_float(o);
}
// sum across the 8 lanes of an oct-group: 3 DPP butterfly steps
__device__ __forceinline__ float sum8(float x) {
  x = dpp_add<0xB1>(x);    // + lane^1 (quad_perm [1,0,3,2])
  x = dpp_add<0x4E>(x);    // + lane^2 (quad_perm [2,3,0,1])
  x = dpp_add<0x141>(x);   // + other quad (row_half_mirror)
  return x;
}

#if __has_builtin(__builtin_elementwise_fma)
#define VFMA(a, b, c) __builtin_elementwise_fma((a), (b), (c))
#else
__device__ __forceinline__ f32x2 VFMA(f32x2 a, f32x2 b, f32x2 c) {
  f32x2 r; r.x = fmaf(a.x, b.x, c.x); r.y = fmaf(a.y, b.y, c.y); return r;
}
#endif

// R11 skeleton (S=4/G=16 tiling, E resident+pinned, h in registers, 1
// barrier/step). R11's null (DS 21->17 instrs: no change) + R10 (+210 cyc
// for deeper DPP) + R4->R9 (-320 for less per-thread work) localize the
// bottleneck in the per-step serial chain: read->dot->reduce->exp->write.
// This round strips the chain TAIL, off-critical-path relocations only:
//  1. exp(h) computed at PREFETCH time (spread at steps 3/5 of the prior
//     chunk, filling the read-latency stall) and pre-selected per oct-lane
//     into one scalar/step (esel). Per-step tail: pw = tot_sel*esel -- no
//     transcendental on the chain. Chunk-head rescale = one exp/8 steps.
//  2. Tail spread across oct lanes: after sum8 every lane has tot0..3;
//     lane oct=o finishes state sb+o (2 cndmask + 1 mul + ds_write_b32,
//     32 conflict-free b32 writes/wave) instead of oct==0 doing 4 states.
//  3. fs = log(pw) + S (R10-proven): 1 log/lane at chunk tails only.
__global__ __attribute__((amdgpu_flat_work_group_size(256, 256),
                          amdgpu_waves_per_eu(1, 1)))
void crf_fwd(const float* __restrict__ h, const float* __restrict__ trans,
             const float* __restrict__ mask, float* __restrict__ out) {
  const int tid  = threadIdx.x;     // 0..255
  const int b    = blockIdx.x;
  const int wid  = tid >> 6;        // wave 0..3
  const int lane = tid & 63;
  const int gl   = lane >> 3;       // group-in-wave 0..7
  const int oct  = lane & 7;        // k-slice 0..7
  const int sb   = 4 * (8 * wid + gl);  // states sb..sb+3
  const int rot  = oct >> 1;
  const int k0   = 16 * oct + 4 * ((0 + rot) & 3);
  const int k1   = 16 * oct + 4 * ((1 + rot) & 3);
  const int k2   = 16 * oct + 4 * ((2 + rot) & 3);
  const int k3   = 16 * oct + 4 * ((3 + rot) & 3);
  const bool o1f = (oct & 1) != 0;
  const bool o2f = (oct & 2) != 0;

  __shared__ __align__(16) float p_lds[2][K];          // double-buffered p
  __shared__ float Mslot[2];                           // tracker, per-chunk parity
  __shared__ float red[8];

  // ---- len = sum(mask[b,:]) (contiguous prefix of 1s) ----
  float msum = mask[b * T + tid] + mask[b * T + 256 + tid];
  #pragma unroll
  for (int off = 32; off > 0; off >>= 1) msum += __shfl_xor(msum, off);
  if (lane == 0) red[wid] = msum;

  // ---- E: 4 states x 16 k-floats in NAMED registers, exp'd, f32x2-split ----
#define EXP4(v) v.x = __expf(v.x); v.y = __expf(v.y); \
                v.z = __expf(v.z); v.w = __expf(v.w);
#define LDE(si) \
  const float* rp##si = trans + (size_t)(sb + si) * K; \
  f32x4 w##si##0 = *reinterpret_cast<const f32x4*>(rp##si + k0); \
  f32x4 w##si##1 = *reinterpret_cast<const f32x4*>(rp##si + k1); \
  f32x4 w##si##2 = *reinterpret_cast<const f32x4*>(rp##si + k2); \
  f32x4 w##si##3 = *reinterpret_cast<const f32x4*>(rp##si + k3); \
  EXP4(w##si##0) EXP4(w##si##1) EXP4(w##si##2) EXP4(w##si##3) \
  f32x2 E##si##0l = __builtin_shufflevector(w##si##0, w##si##0, 0, 1); \
  f32x2 E##si##0h = __builtin_shufflevector(w##si##0, w##si##0, 2, 3); \
  f32x2 E##si##1l = __builtin_shufflevector(w##si##1, w##si##1, 0, 1); \
  f32x2 E##si##1h = __builtin_shufflevector(w##si##1, w##si##1, 2, 3); \
  f32x2 E##si##2l = __builtin_shufflevector(w##si##2, w##si##2, 0, 1); \
  f32x2 E##si##2h = __builtin_shufflevector(w##si##2, w##si##2, 2, 3); \
  f32x2 E##si##3l = __builtin_shufflevector(w##si##3, w##si##3, 0, 1); \
  f32x2 E##si##3h = __builtin_shufflevector(w##si##3, w##si##3, 2, 3);
  LDE(0) LDE(1) LDE(2) LDE(3)
#undef LDE
#define PIN(si) asm volatile("" : "+v"(E##si##0l), "+v"(E##si##0h), \
    "+v"(E##si##1l), "+v"(E##si##1h), "+v"(E##si##2l), "+v"(E##si##2h), \
    "+v"(E##si##3l), "+v"(E##si##3h));
  PIN(0) PIN(1) PIN(2) PIN(3)
#undef PIN

  // ---- h pipeline: 8 in-flight f32x4 loads + per-step selected e^h ----
  const float* hT = h + (size_t)b * T * K + sb;
  f32x4 ld0, ld1, ld2, ld3, ld4, ld5, ld6, ld7;   // transient load regs
  float sA0, sA1, sA2, sA3, sA4, sA5, sA6, sA7;   // esel, current chunk
  float sB0, sB1, sB2, sB3, sB4, sB5, sB6, sB7;   // esel, next chunk
#define LDH(t0) \
  ld0 = *reinterpret_cast<const f32x4*>(hT + (size_t)((t0) + 0) * K); \
  ld1 = *reinterpret_cast<const f32x4*>(hT + (size_t)((t0) + 1) * K); \
  ld2 = *reinterpret_cast<const f32x4*>(hT + (size_t)((t0) + 2) * K); \
  ld3 = *reinterpret_cast<const f32x4*>(hT + (size_t)((t0) + 3) * K); \
  ld4 = *reinterpret_cast<const f32x4*>(hT + (size_t)((t0) + 4) * K); \
  ld5 = *reinterpret_cast<const f32x4*>(hT + (size_t)((t0) + 5) * K); \
  ld6 = *reinterpret_cast<const f32x4*>(hT + (size_t)((t0) + 6) * K); \
  ld7 = *reinterpret_cast<const f32x4*>(hT + (size_t)((t0) + 7) * K); \
  asm volatile("" : "+v"(ld0), "+v"(ld1), "+v"(ld2), "+v"(ld3), \
                    "+v"(ld4), "+v"(ld5), "+v"(ld6), "+v"(ld7));
  // exp the 4 floats of ld##c, select element (oct&3) -> DST
#define EXPSEL(c, DST) { \
    f32x4 e_; \
    e_.x = __expf(ld##c.x); e_.y = __expf(ld##c.y); \
    e_.z = __expf(ld##c.z); e_.w = __expf(ld##c.w); \
    const float lo_ = o1f ? e_.y : e_.x; \
    const float hi_ = o1f ? e_.w : e_.z; \
    DST = o2f ? hi_ : lo_; \
    asm volatile("" : "+v"(DST)); }
#define SELH03(P) EXPSEL(0, P##0) EXPSEL(1, P##1) EXPSEL(2, P##2) EXPSEL(3, P##3)
#define SELH47(P) EXPSEL(4, P##4) EXPSEL(5, P##5) EXPSEL(6, P##6) EXPSEL(7, P##7)

  LDH(0)                    // prologue: chunk 0 loads ...
  SELH03(sA) SELH47(sA)     // ... exp+select (one-time vmcnt wait)

  // ---- init: p(0) one-hot at SOS; tracker = 0 ----
  if (tid < K) p_lds[0][tid] = (tid == 0) ? 1.0f : 0.0f;
  if (tid < 2) Mslot[tid] = 0.0f;
  bar_lgkm();

  const int len = (int)(red[0] + red[1] + red[2] + red[3] + 0.5f);
  const int nch = (len + CH - 1) >> 3;

  float Scur = 0.0f;        // shift of the p about to be read
  float fsS  = NEGV;        // this lane's state (sb + oct&3) true score

#define DOTSI(si) \
      f32x2 u##si = {0.f, 0.f}, v##si = {0.f, 0.f}; \
      u##si = VFMA(E##si##0l, q0l, u##si); v##si = VFMA(E##si##0h, q0h, v##si); \
      u##si = VFMA(E##si##1l, q1l, u##si); v##si = VFMA(E##si##1h, q1h, v##si); \
      u##si = VFMA(E##si##2l, q2l, u##si); v##si = VFMA(E##si##2h, q2h, v##si); \
      u##si = VFMA(E##si##3l, q3l, u##si); v##si = VFMA(E##si##3h, q3h, v##si); \
      const float tot##si = sum8((u##si.x + u##si.y) + (v##si.x + v##si.y));

  // ---- one timestep; cc is a literal 0..7, CURS##cc a named register ----
#define STEP(cc, CURS, NXTS, MC, BASE)                                       \
  if ((BASE) + (cc) < len) {                                                 \
    bar_lgkm();                       /* p(t), Mslot writes now visible */   \
    float Snext = Scur;                                                      \
    float dsf   = 1.0f;                                                      \
    if ((cc) == 0 && (MC)) {                                                 \
      Snext = Mslot[(MC) & 1];                                               \
      dsf   = __expf(Scur - Snext);   /* once per 8 steps, overlaps reads */ \
    }                                                                        \
    const float* pb = p_lds[(cc) & 1];                                       \
    const f32x4 qq0 = *reinterpret_cast<const f32x4*>(pb + k0);              \
    const f32x4 qq1 = *reinterpret_cast<const f32x4*>(pb + k1);              \
    const f32x4 qq2 = *reinterpret_cast<const f32x4*>(pb + k2);              \
    const f32x4 qq3 = *reinterpret_cast<const f32x4*>(pb + k3);              \
    const f32x2 q0l = __builtin_shufflevector(qq0, qq0, 0, 1);               \
    const f32x2 q0h = __builtin_shufflevector(qq0, qq0, 2, 3);               \
    const f32x2 q1l = __builtin_shufflevector(qq1, qq1, 0, 1);               \
    const f32x2 q1h = __builtin_shufflevector(qq1, qq1, 2, 3);               \
    const f32x2 q2l = __builtin_shufflevector(qq2, qq2, 0, 1);               \
    const f32x2 q2h = __builtin_shufflevector(qq2, qq2, 2, 3);               \
    const f32x2 q3l = __builtin_shufflevector(qq3, qq3, 0, 1);               \
    const f32x2 q3h = __builtin_shufflevector(qq3, qq3, 2, 3);               \
    DOTSI(0) DOTSI(1) DOTSI(2) DOTSI(3)                                      \
    /* lane-spread tail: lane oct finishes state sb + (oct&3) */             \
    const float tlo = o1f ? tot1 : tot0;                                     \
    const float thi = o1f ? tot3 : tot2;                                     \
    float pwo = (o2f ? thi : tlo) * CURS##cc;                                \
    if ((cc) == 0) pwo *= dsf;                                               \
    if (oct < 4) p_lds[((cc) & 1) ^ 1][sb + oct] = pwo;                      \
    if ((cc) == 0 && (BASE) + CH < len) { LDH((BASE) + CH) }                 \
    if ((cc) == 3 && (BASE) + CH < len) { SELH03(NXTS) }                     \
    if ((cc) == 5 && (BASE) + CH < len) { SELH47(NXTS) }                     \
    if ((cc) == CH - 1 || (BASE) + (cc) == len - 1) {                        \
      fsS = __logf(pwo) + Snext;      /* true score, frame-corrected */      \
      if (tid == 2) Mslot[((MC) + 1) & 1] = fsS;   /* tracker = state 2 */   \
    }                                                                        \
    Scur = Snext;                                                            \
  }

#define CHUNK(CURS, NXTS, MC, BASE)                                          \
  { STEP(0, CURS, NXTS, MC, BASE) STEP(1, CURS, NXTS, MC, BASE)              \
    STEP(2, CURS, NXTS, MC, BASE) STEP(3, CURS, NXTS, MC, BASE)              \
    STEP(4, CURS, NXTS, MC, BASE) STEP(5, CURS, NXTS, MC, BASE)              \
    STEP(6, CURS, NXTS, MC, BASE) STEP(7, CURS, NXTS, MC, BASE) }

  for (int mc = 0; mc < nch; mc += 2) {
    CHUNK(sA, sB, mc, mc << 3)
    if (mc + 1 < nch) { CHUNK(sB, sA, mc + 1, (mc + 1) << 3) }
  }
#undef CHUNK
#undef STEP
#undef DOTSI
#undef SELH03
#undef SELH47
#undef EXPSEL
#undef LDH
#undef EXP4

  // ---- epilogue: out[b] = logsumexp_j(fs_j + trans[EOS, j]) ----
  // Each of the 128 states appears exactly once across oct<4 lanes.
  const float trEo = trans[K + sb + (oct & 3)];
  const float ffv = (oct < 4) ? (fsS + trEo) : NEGV;
  float mx = ffv;
  #pragma unroll
  for (int off = 32; off > 0; off >>= 1) mx = fmaxf(mx, __shfl_xor(mx, off));
  if (lane == 0) red[wid] = mx;
  bar_lgkm();
  const float fm = fmaxf(fmaxf(red[0], red[1]), fmaxf(red[2], red[3]));
  float e = (oct < 4) ? __expf(ffv - fm) : 0.0f;
  #pragma unroll
  for (int off = 32; off > 0; off >>= 1) e += __shfl_xor(e, off);
  if (lane == 0) red[4 + wid] = e;
  bar_lgkm();
  if (tid == 0) out[b] = fm + __logf((red[4] + red[5]) + (red[6] + red[7]));
}

extern "C" void kernel_launch(void* const* d_in, const int* in_sizes, int n_in,
                              void* d_out, int out_size, void* d_ws, size_t ws_size,
                              hipStream_t stream) {
  const float* h     = (const float*)d_in[0];  // (B,T,K) fp32
  const float* trans = (const float*)d_in[1];  // (K,K)   fp32
  const float* mask  = (const float*)d_in[2];  // (B,T)   fp32
  float* out = (float*)d_out;                  // (B,)    fp32
  const int B = in_sizes[0] / (T * K);         // 256
  crf_fwd<<<B, 256, 0, stream>>>(h, trans, mask, out);
}